// Round 1
// 554.495 us; speedup vs baseline: 1.0807x; 1.0807x over previous
//
#include <hip/hip_runtime.h>
#include <hip/hip_bf16.h>

// RT-DETR multi-scale deformable attention, MI355X (gfx950).
// Round 5: dedicated value-projection GEMM (k_vproj): Wv resident in LDS
// (barrier-free K-loop, A streamed global->reg->MFMA, persistent blocks,
// LDS-transposed coalesced bf16x8 output stores). Small GEMMs unchanged.

#define BS 8
#define LQ 300
#define LEN_V 34000
#define ED 256
#define NH 8
#define NL 4
#define NP 4

#define LDT 40  // padded LDS row stride (bf16) for k_gemm tiles

#define VSTRIPS 2125  // 272000 / 128

typedef short short8 __attribute__((ext_vector_type(8)));
typedef short sv4 __attribute__((ext_vector_type(4)));
typedef float f32x4 __attribute__((ext_vector_type(4)));

__device__ __forceinline__ short8 cvt8_reg(float4 a, float4 b) {
  union { short8 v; __hip_bfloat16 h[8]; } u;
  u.h[0] = __float2bfloat16(a.x); u.h[1] = __float2bfloat16(a.y);
  u.h[2] = __float2bfloat16(a.z); u.h[3] = __float2bfloat16(a.w);
  u.h[4] = __float2bfloat16(b.x); u.h[5] = __float2bfloat16(b.y);
  u.h[6] = __float2bfloat16(b.z); u.h[7] = __float2bfloat16(b.w);
  return u.v;
}

__device__ __forceinline__ void cvt8_store(__hip_bfloat16* dst, float4 a, float4 b) {
  *(short8*)dst = cvt8_reg(a, b);
}

__device__ __forceinline__ void store_elem(float* p, float x) { *p = x; }
__device__ __forceinline__ void store_elem(__hip_bfloat16* p, float x) {
  *p = __float2bfloat16(x);
}

// ---------------- Value projection: C[272000 x 256] = A @ Wv^T + bv (bf16 out)
// Persistent blocks (grid=256), 512 thr = 8 waves (2 row-halves x 4 col-quads).
// Wv (256x256) staged ONCE per block as bf16 in LDS [256][264] (pad 8 -> the
// ds_read_b128 fragment pattern is exactly 8 accesses/bank = conflict-free).
// K-loop has NO barriers: A fragments stream global->reg (double-buffered,
// 8 outstanding dwordx4 per wave = 8KB in flight), cvt to bf16 in-register.
// Epilogue: 4 passes of 32 rows through small LDS buffer -> 512B-contiguous
// short8 stores (kills the 1.9x partial-line write amplification).
__global__ __launch_bounds__(512) void k_vproj(
    const float* __restrict__ A, const float* __restrict__ B,
    const float* __restrict__ bias, __hip_bfloat16* __restrict__ C) {
  __shared__ __align__(16) __hip_bfloat16 Bs[256][264];  // 135,168 B
  __shared__ __align__(16) __hip_bfloat16 Cs[32][264];   //  16,896 B

  const int t = threadIdx.x;

  // ---- stage Wv -> bf16 LDS (once per block) ----
  for (int i = t; i < 256 * 64; i += 512) {
    const int n = i >> 6;
    const int kf = (i & 63) * 4;
    const float4 b4 = *(const float4*)(B + (size_t)n * ED + kf);
    union { sv4 v; __hip_bfloat16 h[4]; } u;
    u.h[0] = __float2bfloat16(b4.x);
    u.h[1] = __float2bfloat16(b4.y);
    u.h[2] = __float2bfloat16(b4.z);
    u.h[3] = __float2bfloat16(b4.w);
    *(sv4*)&Bs[n][kf] = u.v;
  }
  __syncthreads();

  const int wave = t >> 6;
  const int lane = t & 63;
  const int wr = wave >> 2;        // row-half 0..1  (64 rows each)
  const int wc = wave & 3;         // col-quad 0..3  (64 cols each)
  const int fr = lane & 15;
  const int fk = (lane >> 4) * 8;
  const int rq = (lane >> 4) * 4;

  float bias_v[4];
#pragma unroll
  for (int ni = 0; ni < 4; ++ni) bias_v[ni] = bias[wc * 64 + ni * 16 + fr];

  for (int strip = blockIdx.x; strip < VSTRIPS; strip += gridDim.x) {
    const size_t row0 = (size_t)strip * 128;
    const float* gA = A + (row0 + wr * 64 + fr) * ED + fk;

    f32x4 acc[4][4];
#pragma unroll
    for (int i = 0; i < 4; ++i)
#pragma unroll
      for (int j = 0; j < 4; ++j) acc[i][j] = (f32x4){0.f, 0.f, 0.f, 0.f};

    float4 c0[4], c1[4];
#pragma unroll
    for (int mi = 0; mi < 4; ++mi) {
      c0[mi] = *(const float4*)(gA + mi * 16 * ED);
      c1[mi] = *(const float4*)(gA + mi * 16 * ED + 4);
    }

    for (int kk = 0; kk < ED; kk += 32) {
      float4 p0[4], p1[4];
      if (kk < ED - 32) {
#pragma unroll
        for (int mi = 0; mi < 4; ++mi) {
          p0[mi] = *(const float4*)(gA + mi * 16 * ED + kk + 32);
          p1[mi] = *(const float4*)(gA + mi * 16 * ED + kk + 36);
        }
      }
      short8 af[4], bf[4];
#pragma unroll
      for (int mi = 0; mi < 4; ++mi) af[mi] = cvt8_reg(c0[mi], c1[mi]);
#pragma unroll
      for (int ni = 0; ni < 4; ++ni)
        bf[ni] = *(const short8*)&Bs[wc * 64 + ni * 16 + fr][kk + fk];
#pragma unroll
      for (int mi = 0; mi < 4; ++mi)
#pragma unroll
        for (int ni = 0; ni < 4; ++ni)
          acc[mi][ni] = __builtin_amdgcn_mfma_f32_16x16x32_bf16(
              af[mi], bf[ni], acc[mi][ni], 0, 0, 0);
#pragma unroll
      for (int mi = 0; mi < 4; ++mi) { c0[mi] = p0[mi]; c1[mi] = p1[mi]; }
    }

    // ---- epilogue: 4 passes x 32 rows through Cs, coalesced stores ----
#pragma unroll
    for (int p = 0; p < 4; ++p) {
      if (wr == (p >> 1)) {
        const int mib = (p & 1) * 2;
#pragma unroll
        for (int ni = 0; ni < 4; ++ni) {
          const int col = wc * 64 + ni * 16 + fr;
#pragma unroll
          for (int mj = 0; mj < 2; ++mj) {
            const int mi = mib + mj;
            const int rl = mj * 16 + rq;  // row within this 32-row pass
#pragma unroll
            for (int r = 0; r < 4; ++r)
              Cs[rl + r][col] = __float2bfloat16(acc[mi][ni][r] + bias_v[ni]);
          }
        }
      }
      __syncthreads();
      {
        const int rr = t >> 5;          // 0..15
        const int cb = (t & 31) * 8;    // bf16 col
        const size_t gr = row0 + p * 32;
        *(short8*)(C + (gr + rr) * ED + cb) = *(const short8*)&Cs[rr][cb];
        *(short8*)(C + (gr + rr + 16) * ED + cb) = *(const short8*)&Cs[rr + 16][cb];
      }
      __syncthreads();
    }
  }
}

// ---------------- Generic MFMA GEMM: C[M x ldc] = A[M x 256] @ B[N x 256]^T + bias
// Block 256 thr (4 waves), tile 128x128, BK=32, K=256. grid=(ceil(M/128), N/128).
template <typename OutT>
__global__ __launch_bounds__(256) void k_gemm(
    const float* __restrict__ A, const float* __restrict__ B,
    const float* __restrict__ bias, OutT* __restrict__ C, int M, int ldc) {
  __shared__ __align__(16) __hip_bfloat16 As[128][LDT];
  __shared__ __align__(16) __hip_bfloat16 Bs[128][LDT];

  const int t = threadIdx.x;
  const size_t row0 = (size_t)blockIdx.x * 128;
  const int n0 = blockIdx.y * 128;

  const int sr = t >> 2;          // staging row 0..63 (+64 for slab 1)
  const int sc = (t & 3) * 8;     // staging f32 col offset

  const int wave = t >> 6;
  const int lane = t & 63;
  const int mw = (wave & 1) * 64;
  const int nw = (wave >> 1) * 64;
  const int fr = lane & 15;
  const int fk = (lane >> 4) * 8;

  f32x4 acc[4][4];
#pragma unroll
  for (int i = 0; i < 4; ++i)
#pragma unroll
    for (int j = 0; j < 4; ++j) acc[i][j] = (f32x4){0.f, 0.f, 0.f, 0.f};

  const size_t rA0 = min(row0 + sr, (size_t)(M - 1));
  const size_t rA1 = min(row0 + sr + 64, (size_t)(M - 1));
  const float* gA0 = A + rA0 * ED + sc;
  const float* gA1 = A + rA1 * ED + sc;
  const float* gB0 = B + (size_t)(n0 + sr) * ED + sc;
  const float* gB1 = B + (size_t)(n0 + sr + 64) * ED + sc;

  for (int kk = 0; kk < ED; kk += 32) {
    float4 a00 = ((const float4*)(gA0 + kk))[0];
    float4 a01 = ((const float4*)(gA0 + kk))[1];
    float4 a10 = ((const float4*)(gA1 + kk))[0];
    float4 a11 = ((const float4*)(gA1 + kk))[1];
    float4 b00 = ((const float4*)(gB0 + kk))[0];
    float4 b01 = ((const float4*)(gB0 + kk))[1];
    float4 b10 = ((const float4*)(gB1 + kk))[0];
    float4 b11 = ((const float4*)(gB1 + kk))[1];
    __syncthreads();  // protect LDS reuse from previous iter
    cvt8_store(&As[sr][sc], a00, a01);
    cvt8_store(&As[sr + 64][sc], a10, a11);
    cvt8_store(&Bs[sr][sc], b00, b01);
    cvt8_store(&Bs[sr + 64][sc], b10, b11);
    __syncthreads();

    short8 afrag[4], bfrag[4];
#pragma unroll
    for (int mi = 0; mi < 4; ++mi)
      afrag[mi] = *(const short8*)&As[mw + mi * 16 + fr][fk];
#pragma unroll
    for (int ni = 0; ni < 4; ++ni)
      bfrag[ni] = *(const short8*)&Bs[nw + ni * 16 + fr][fk];

#pragma unroll
    for (int mi = 0; mi < 4; ++mi)
#pragma unroll
      for (int ni = 0; ni < 4; ++ni)
        acc[mi][ni] = __builtin_amdgcn_mfma_f32_16x16x32_bf16(
            afrag[mi], bfrag[ni], acc[mi][ni], 0, 0, 0);
  }

  // epilogue: C/D layout col=lane&15, row=(lane>>4)*4+reg
  const int rq = (lane >> 4) * 4;
#pragma unroll
  for (int ni = 0; ni < 4; ++ni) {
    const int col = n0 + nw + ni * 16 + fr;
    const float bias_v = bias[col];
#pragma unroll
    for (int mi = 0; mi < 4; ++mi) {
      const size_t rbase = row0 + mw + mi * 16 + rq;
#pragma unroll
      for (int r = 0; r < 4; ++r) {
        const size_t row = rbase + r;
        if (row < (size_t)M)
          store_elem(&C[row * (size_t)ldc + col], acc[mi][ni][r] + bias_v);
      }
    }
  }
}

// ---------------- Concat Woff(256x256) + Wattn(128x256) -> Wcat(384x256) ------
__global__ __launch_bounds__(256) void k_concat(
    const float* __restrict__ Woff, const float* __restrict__ boff,
    const float* __restrict__ Wattn, const float* __restrict__ battn,
    float* __restrict__ Wcat, float* __restrict__ bcat) {
  const int row = blockIdx.x;  // 0..383
  const int t = threadIdx.x;
  const float* src = (row < 256) ? (Woff + (size_t)row * ED)
                                 : (Wattn + (size_t)(row - 256) * ED);
  Wcat[(size_t)row * ED + t] = src[t];
  if (t == 0) bcat[row] = (row < 256) ? boff[row] : battn[row - 256];
}

// ---------------- Post: loc + softmax, in-place in offs[2400 x 384] -----------
__global__ __launch_bounds__(256) void k_post(
    const float* __restrict__ refp, float* __restrict__ offs) {
  __shared__ float lg[128];
  const int t = threadIdx.x;
  const int bq = blockIdx.x;
  float* row = offs + (size_t)bq * 384;
  if (t < 128) lg[t] = row[256 + t];
  const float o = row[t];
  const int c = t & 1;
  const int l = (t >> 3) & 3;
  const float norm = (float)(160 >> l);
  const float r = refp[((size_t)bq * NL + l) * 2 + c];
  __syncthreads();
  row[t] = r + o / norm;
  if (t < NH) {
    float m = -1e30f;
#pragma unroll
    for (int i = 0; i < 16; ++i) m = fmaxf(m, lg[t * 16 + i]);
    float e[16];
    float s = 0.f;
#pragma unroll
    for (int i = 0; i < 16; ++i) {
      e[i] = expf(lg[t * 16 + i] - m);
      s += e[i];
    }
    const float inv = 1.f / s;
#pragma unroll
    for (int i = 0; i < 16; ++i) row[256 + t * 16 + i] = e[i] * inv;
  }
}

// ---------------- Sample: point-parallel bilinear gather + LDS reduce ---------
__device__ __forceinline__ float sample_one(const __hip_bfloat16* __restrict__ vb,
                                            int st, int W, int xi, int yi, int ch) {
  const bool valid = (xi >= 0) & (xi < W) & (yi >= 0) & (yi < W);
  const int xc = min(max(xi, 0), W - 1);
  const int yc = min(max(yi, 0), W - 1);
  const float g = __bfloat162float(vb[((size_t)(st + yc * W + xc)) * ED + ch]);
  return valid ? g : 0.f;
}

__global__ __launch_bounds__(512) void k_sample(
    const __hip_bfloat16* __restrict__ v, const float* __restrict__ offs,
    float* __restrict__ inner) {
  __shared__ float part[16][256];
  __shared__ float slo[256];
  __shared__ float saw[128];
  const int t = threadIdx.x;
  const int bq = blockIdx.x;
  const int b = bq / LQ;
  const float* rowq = offs + (size_t)bq * 384;
  if (t < 256) slo[t] = rowq[t];
  else if (t < 384) saw[t - 256] = rowq[t];
  __syncthreads();

  const int pi = t >> 5;  // 0..15
  const int d = t & 31;
  const int l = pi >> 2;
  const int p = pi & 3;
  const int W = 160 >> l;
  const int st = (l == 0) ? 0 : (l == 1) ? 25600 : (l == 2) ? 32000 : 33600;
  const __hip_bfloat16* vb = v + (size_t)b * LEN_V * ED;

#pragma unroll
  for (int h = 0; h < NH; ++h) {
    const int base = ((h * NL + l) * NP + p) * 2;
    const float lx = slo[base];
    const float ly = slo[base + 1];
    const float w = saw[h * 16 + pi];
    const float x = lx * (float)W - 0.5f;
    const float y = ly * (float)W - 0.5f;
    const float x0f = floorf(x);
    const float y0f = floorf(y);
    const float wx = x - x0f;
    const float wy = y - y0f;
    const int x0 = (int)x0f;
    const int y0 = (int)y0f;
    const int ch = h * 32 + d;
    const float g00 = sample_one(vb, st, W, x0, y0, ch);
    const float g01 = sample_one(vb, st, W, x0 + 1, y0, ch);
    const float g10 = sample_one(vb, st, W, x0, y0 + 1, ch);
    const float g11 = sample_one(vb, st, W, x0 + 1, y0 + 1, ch);
    const float vxy = (g00 * (1.f - wx) + g01 * wx) * (1.f - wy) +
                      (g10 * (1.f - wx) + g11 * wx) * wy;
    part[pi][ch] = w * vxy;
  }
  __syncthreads();
  if (t < 256) {
    float s = 0.f;
#pragma unroll
    for (int q = 0; q < 16; ++q) s += part[q][t];
    inner[(size_t)bq * ED + t] = s;
  }
}

extern "C" void kernel_launch(void* const* d_in, const int* in_sizes, int n_in,
                              void* d_out, int out_size, void* d_ws, size_t ws_size,
                              hipStream_t stream) {
  const float* query = (const float*)d_in[0];
  const float* refp  = (const float*)d_in[1];
  const float* value = (const float*)d_in[2];
  const float* Wv    = (const float*)d_in[3];
  const float* bv    = (const float*)d_in[4];
  const float* Woff  = (const float*)d_in[5];
  const float* boff  = (const float*)d_in[6];
  const float* Wattn = (const float*)d_in[7];
  const float* battn = (const float*)d_in[8];
  const float* Wout  = (const float*)d_in[9];
  const float* bout  = (const float*)d_in[10];
  float* out = (float*)d_out;

  char* ws = (char*)d_ws;
  __hip_bfloat16* v = (__hip_bfloat16*)ws;        // 139,264,000 B
  size_t off = (size_t)BS * LEN_V * ED * 2;
  float* offs = (float*)(ws + off);               // 2400*384*4 = 3.69 MB
  off += (size_t)BS * LQ * 384 * 4;
  float* inner = (float*)(ws + off);              // 2400*256*4 = 2.46 MB
  off += (size_t)BS * LQ * 256 * 4;
  float* Wcat = (float*)(ws + off);               // 384*256*4
  off += (size_t)384 * ED * 4;
  float* bcat = (float*)(ws + off);               // 384*4

  const int M_Q = BS * LQ;  // 2400

  k_concat<<<384, 256, 0, stream>>>(Woff, boff, Wattn, battn, Wcat, bcat);
  // value proj: persistent full-N blocks, Wv resident in LDS
  k_vproj<<<256, 512, 0, stream>>>(value, Wv, bv, v);
  // query proj (offsets + attn logits): M=2400 -> 19 blocks, N=384 -> 3
  k_gemm<float><<<dim3(19, 3), 256, 0, stream>>>(
      query, Wcat, bcat, offs, M_Q, 384);
  k_post<<<M_Q, 256, 0, stream>>>(refp, offs);
  k_sample<<<M_Q, 512, 0, stream>>>(v, offs, inner);
  // out proj: M=2400, N=256
  k_gemm<float><<<dim3(19, 2), 256, 0, stream>>>(
      inner, Wout, bout, out, M_Q, ED);
}

// Round 2
// 507.727 us; speedup vs baseline: 1.1802x; 1.0921x over previous
//
#include <hip/hip_runtime.h>
#include <hip/hip_bf16.h>

// RT-DETR multi-scale deformable attention, MI355X (gfx950).
// Round 6: k_vproj at 16 waves/CU (1024-thr block, 32x64 wave tile, <=128 reg)
// to cover HBM latency; small GEMMs retiled 64x64/BK=64 for 4x block count.

#define BS 8
#define LQ 300
#define LEN_V 34000
#define ED 256
#define NH 8
#define NL 4
#define NP 4

#define VSTRIPS 2125  // 272000 / 128

typedef short short8 __attribute__((ext_vector_type(8)));
typedef short sv4 __attribute__((ext_vector_type(4)));
typedef float f32x4 __attribute__((ext_vector_type(4)));

__device__ __forceinline__ short8 cvt8_reg(float4 a, float4 b) {
  union { short8 v; __hip_bfloat16 h[8]; } u;
  u.h[0] = __float2bfloat16(a.x); u.h[1] = __float2bfloat16(a.y);
  u.h[2] = __float2bfloat16(a.z); u.h[3] = __float2bfloat16(a.w);
  u.h[4] = __float2bfloat16(b.x); u.h[5] = __float2bfloat16(b.y);
  u.h[6] = __float2bfloat16(b.z); u.h[7] = __float2bfloat16(b.w);
  return u.v;
}

__device__ __forceinline__ void cvt8_store(__hip_bfloat16* dst, float4 a, float4 b) {
  *(short8*)dst = cvt8_reg(a, b);
}

// ---------------- Value projection: C[272000 x 256] = A @ Wv^T + bv (bf16 out)
// 256 persistent blocks x 1024 thr (16 waves = 4/SIMD, 50% occupancy).
// Wv staged once as bf16 LDS [256][264]. Wave tile 32 rows x 64 cols
// (acc[2][4]) -> ~100 regs, fits the 128-reg cap of 4 waves/SIMD.
// K-loop barrier-free: A streams global->reg (1-deep prefetch), cvt in-reg.
// Epilogue: 4 passes of 32 rows through Cs -> 512B-contiguous short8 stores.
__global__ __launch_bounds__(1024, 4) void k_vproj(
    const float* __restrict__ A, const float* __restrict__ B,
    const float* __restrict__ bias, __hip_bfloat16* __restrict__ C) {
  __shared__ __align__(16) __hip_bfloat16 Bs[256][264];  // 135,168 B
  __shared__ __align__(16) __hip_bfloat16 Cs[32][264];   //  16,896 B

  const int t = threadIdx.x;

  // ---- stage Wv -> bf16 LDS (once per block) ----
  for (int i = t; i < 256 * 64; i += 1024) {
    const int n = i >> 6;
    const int kf = (i & 63) * 4;
    const float4 b4 = *(const float4*)(B + (size_t)n * ED + kf);
    union { sv4 v; __hip_bfloat16 h[4]; } u;
    u.h[0] = __float2bfloat16(b4.x);
    u.h[1] = __float2bfloat16(b4.y);
    u.h[2] = __float2bfloat16(b4.z);
    u.h[3] = __float2bfloat16(b4.w);
    *(sv4*)&Bs[n][kf] = u.v;
  }
  __syncthreads();

  const int wave = t >> 6;
  const int lane = t & 63;
  const int wr = wave >> 2;        // row-group 0..3 (32 rows each)
  const int wc = wave & 3;         // col-quad 0..3  (64 cols each)
  const int fr = lane & 15;
  const int fk = (lane >> 4) * 8;
  const int rq = (lane >> 4) * 4;

  float bias_v[4];
#pragma unroll
  for (int ni = 0; ni < 4; ++ni) bias_v[ni] = bias[wc * 64 + ni * 16 + fr];

  for (int strip = blockIdx.x; strip < VSTRIPS; strip += gridDim.x) {
    const size_t row0 = (size_t)strip * 128;
    const float* gA = A + (row0 + wr * 32 + fr) * ED + fk;

    f32x4 acc[2][4];
#pragma unroll
    for (int i = 0; i < 2; ++i)
#pragma unroll
      for (int j = 0; j < 4; ++j) acc[i][j] = (f32x4){0.f, 0.f, 0.f, 0.f};

    float4 c0[2], c1[2];
#pragma unroll
    for (int mi = 0; mi < 2; ++mi) {
      c0[mi] = *(const float4*)(gA + mi * 16 * ED);
      c1[mi] = *(const float4*)(gA + mi * 16 * ED + 4);
    }

    for (int kk = 0; kk < ED; kk += 32) {
      float4 p0[2], p1[2];
      if (kk < ED - 32) {
#pragma unroll
        for (int mi = 0; mi < 2; ++mi) {
          p0[mi] = *(const float4*)(gA + mi * 16 * ED + kk + 32);
          p1[mi] = *(const float4*)(gA + mi * 16 * ED + kk + 36);
        }
      }
      short8 af[2], bf[4];
#pragma unroll
      for (int mi = 0; mi < 2; ++mi) af[mi] = cvt8_reg(c0[mi], c1[mi]);
#pragma unroll
      for (int ni = 0; ni < 4; ++ni)
        bf[ni] = *(const short8*)&Bs[wc * 64 + ni * 16 + fr][kk + fk];
#pragma unroll
      for (int mi = 0; mi < 2; ++mi)
#pragma unroll
        for (int ni = 0; ni < 4; ++ni)
          acc[mi][ni] = __builtin_amdgcn_mfma_f32_16x16x32_bf16(
              af[mi], bf[ni], acc[mi][ni], 0, 0, 0);
#pragma unroll
      for (int mi = 0; mi < 2; ++mi) { c0[mi] = p0[mi]; c1[mi] = p1[mi]; }
    }

    // ---- epilogue: 4 passes x 32 rows through Cs, coalesced stores ----
#pragma unroll
    for (int p = 0; p < 4; ++p) {
      if (wr == p) {
#pragma unroll
        for (int ni = 0; ni < 4; ++ni) {
          const int col = wc * 64 + ni * 16 + fr;
#pragma unroll
          for (int mi = 0; mi < 2; ++mi) {
            const int rl = mi * 16 + rq;
#pragma unroll
            for (int r = 0; r < 4; ++r)
              Cs[rl + r][col] = __float2bfloat16(acc[mi][ni][r] + bias_v[ni]);
          }
        }
      }
      __syncthreads();
      {
        const int rr = t >> 5;          // 0..31
        const int cb = (t & 31) * 8;    // bf16 col
        const size_t gr = row0 + p * 32 + rr;
        *(short8*)(C + gr * ED + cb) = *(const short8*)&Cs[rr][cb];
      }
      __syncthreads();
    }
  }
}

// ---------------- Small MFMA GEMM: C[M x ldc] = A[M x 256] @ B[N x 256]^T + bias
// Block 256 thr (4 waves), tile 64x64, BK=64 (4 K-steps), K=256.
// grid = (ceil(M/64), N/64). 18.4KB LDS -> many blocks/CU, high grid count.
#define LDT64 72  // 64 + 8 pad: stride 144B = 36 words == 4 mod 32 (2-way max)

template <typename OutT>
__global__ __launch_bounds__(256) void k_gemm64(
    const float* __restrict__ A, const float* __restrict__ B,
    const float* __restrict__ bias, OutT* __restrict__ C, int M, int ldc) {
  __shared__ __align__(16) __hip_bfloat16 As[64][LDT64];
  __shared__ __align__(16) __hip_bfloat16 Bs[64][LDT64];

  const int t = threadIdx.x;
  const size_t row0 = (size_t)blockIdx.x * 64;
  const int n0 = blockIdx.y * 64;

  const int sr = t >> 2;          // staging row 0..63
  const int sc = (t & 3) * 16;    // staging f32 col offset (16 floats/thread)

  const int wave = t >> 6;
  const int lane = t & 63;
  const int mw = (wave & 1) * 32;
  const int nw = (wave >> 1) * 32;
  const int fr = lane & 15;
  const int fk = (lane >> 4) * 8;

  f32x4 acc[2][2];
#pragma unroll
  for (int i = 0; i < 2; ++i)
#pragma unroll
    for (int j = 0; j < 2; ++j) acc[i][j] = (f32x4){0.f, 0.f, 0.f, 0.f};

  const size_t rA = min(row0 + sr, (size_t)(M - 1));
  const float* gA = A + rA * ED + sc;
  const float* gB = B + (size_t)(n0 + sr) * ED + sc;

  for (int kk = 0; kk < ED; kk += 64) {
    float4 a0 = ((const float4*)(gA + kk))[0];
    float4 a1 = ((const float4*)(gA + kk))[1];
    float4 a2 = ((const float4*)(gA + kk))[2];
    float4 a3 = ((const float4*)(gA + kk))[3];
    float4 b0 = ((const float4*)(gB + kk))[0];
    float4 b1 = ((const float4*)(gB + kk))[1];
    float4 b2 = ((const float4*)(gB + kk))[2];
    float4 b3 = ((const float4*)(gB + kk))[3];
    __syncthreads();  // protect LDS reuse from previous iter
    cvt8_store(&As[sr][sc], a0, a1);
    cvt8_store(&As[sr][sc + 8], a2, a3);
    cvt8_store(&Bs[sr][sc], b0, b1);
    cvt8_store(&Bs[sr][sc + 8], b2, b3);
    __syncthreads();

#pragma unroll
    for (int ks = 0; ks < 2; ++ks) {
      short8 afrag[2], bfrag[2];
#pragma unroll
      for (int mi = 0; mi < 2; ++mi)
        afrag[mi] = *(const short8*)&As[mw + mi * 16 + fr][ks * 32 + fk];
#pragma unroll
      for (int ni = 0; ni < 2; ++ni)
        bfrag[ni] = *(const short8*)&Bs[nw + ni * 16 + fr][ks * 32 + fk];
#pragma unroll
      for (int mi = 0; mi < 2; ++mi)
#pragma unroll
        for (int ni = 0; ni < 2; ++ni)
          acc[mi][ni] = __builtin_amdgcn_mfma_f32_16x16x32_bf16(
              afrag[mi], bfrag[ni], acc[mi][ni], 0, 0, 0);
    }
  }

  // epilogue: C/D layout col=lane&15, row=(lane>>4)*4+reg
  const int rq = (lane >> 4) * 4;
#pragma unroll
  for (int ni = 0; ni < 2; ++ni) {
    const int col = n0 + nw + ni * 16 + fr;
    const float bias_v = bias[col];
#pragma unroll
    for (int mi = 0; mi < 2; ++mi) {
      const size_t rbase = row0 + mw + mi * 16 + rq;
#pragma unroll
      for (int r = 0; r < 4; ++r) {
        const size_t row = rbase + r;
        if (row < (size_t)M)
          C[row * (size_t)ldc + col] = acc[mi][ni][r] + bias_v;
      }
    }
  }
}

// ---------------- Concat Woff(256x256) + Wattn(128x256) -> Wcat(384x256) ------
__global__ __launch_bounds__(256) void k_concat(
    const float* __restrict__ Woff, const float* __restrict__ boff,
    const float* __restrict__ Wattn, const float* __restrict__ battn,
    float* __restrict__ Wcat, float* __restrict__ bcat) {
  const int row = blockIdx.x;  // 0..383
  const int t = threadIdx.x;
  const float* src = (row < 256) ? (Woff + (size_t)row * ED)
                                 : (Wattn + (size_t)(row - 256) * ED);
  Wcat[(size_t)row * ED + t] = src[t];
  if (t == 0) bcat[row] = (row < 256) ? boff[row] : battn[row - 256];
}

// ---------------- Post: loc + softmax, in-place in offs[2400 x 384] -----------
__global__ __launch_bounds__(256) void k_post(
    const float* __restrict__ refp, float* __restrict__ offs) {
  __shared__ float lg[128];
  const int t = threadIdx.x;
  const int bq = blockIdx.x;
  float* row = offs + (size_t)bq * 384;
  if (t < 128) lg[t] = row[256 + t];
  const float o = row[t];
  const int c = t & 1;
  const int l = (t >> 3) & 3;
  const float norm = (float)(160 >> l);
  const float r = refp[((size_t)bq * NL + l) * 2 + c];
  __syncthreads();
  row[t] = r + o / norm;
  if (t < NH) {
    float m = -1e30f;
#pragma unroll
    for (int i = 0; i < 16; ++i) m = fmaxf(m, lg[t * 16 + i]);
    float e[16];
    float s = 0.f;
#pragma unroll
    for (int i = 0; i < 16; ++i) {
      e[i] = expf(lg[t * 16 + i] - m);
      s += e[i];
    }
    const float inv = 1.f / s;
#pragma unroll
    for (int i = 0; i < 16; ++i) row[256 + t * 16 + i] = e[i] * inv;
  }
}

// ---------------- Sample: point-parallel bilinear gather + LDS reduce ---------
__device__ __forceinline__ float sample_one(const __hip_bfloat16* __restrict__ vb,
                                            int st, int W, int xi, int yi, int ch) {
  const bool valid = (xi >= 0) & (xi < W) & (yi >= 0) & (yi < W);
  const int xc = min(max(xi, 0), W - 1);
  const int yc = min(max(yi, 0), W - 1);
  const float g = __bfloat162float(vb[((size_t)(st + yc * W + xc)) * ED + ch]);
  return valid ? g : 0.f;
}

__global__ __launch_bounds__(512) void k_sample(
    const __hip_bfloat16* __restrict__ v, const float* __restrict__ offs,
    float* __restrict__ inner) {
  __shared__ float part[16][256];
  __shared__ float slo[256];
  __shared__ float saw[128];
  const int t = threadIdx.x;
  const int bq = blockIdx.x;
  const int b = bq / LQ;
  const float* rowq = offs + (size_t)bq * 384;
  if (t < 256) slo[t] = rowq[t];
  else if (t < 384) saw[t - 256] = rowq[t];
  __syncthreads();

  const int pi = t >> 5;  // 0..15
  const int d = t & 31;
  const int l = pi >> 2;
  const int p = pi & 3;
  const int W = 160 >> l;
  const int st = (l == 0) ? 0 : (l == 1) ? 25600 : (l == 2) ? 32000 : 33600;
  const __hip_bfloat16* vb = v + (size_t)b * LEN_V * ED;

#pragma unroll
  for (int h = 0; h < NH; ++h) {
    const int base = ((h * NL + l) * NP + p) * 2;
    const float lx = slo[base];
    const float ly = slo[base + 1];
    const float w = saw[h * 16 + pi];
    const float x = lx * (float)W - 0.5f;
    const float y = ly * (float)W - 0.5f;
    const float x0f = floorf(x);
    const float y0f = floorf(y);
    const float wx = x - x0f;
    const float wy = y - y0f;
    const int x0 = (int)x0f;
    const int y0 = (int)y0f;
    const int ch = h * 32 + d;
    const float g00 = sample_one(vb, st, W, x0, y0, ch);
    const float g01 = sample_one(vb, st, W, x0 + 1, y0, ch);
    const float g10 = sample_one(vb, st, W, x0, y0 + 1, ch);
    const float g11 = sample_one(vb, st, W, x0 + 1, y0 + 1, ch);
    const float vxy = (g00 * (1.f - wx) + g01 * wx) * (1.f - wy) +
                      (g10 * (1.f - wx) + g11 * wx) * wy;
    part[pi][ch] = w * vxy;
  }
  __syncthreads();
  if (t < 256) {
    float s = 0.f;
#pragma unroll
    for (int q = 0; q < 16; ++q) s += part[q][t];
    inner[(size_t)bq * ED + t] = s;
  }
}

extern "C" void kernel_launch(void* const* d_in, const int* in_sizes, int n_in,
                              void* d_out, int out_size, void* d_ws, size_t ws_size,
                              hipStream_t stream) {
  const float* query = (const float*)d_in[0];
  const float* refp  = (const float*)d_in[1];
  const float* value = (const float*)d_in[2];
  const float* Wv    = (const float*)d_in[3];
  const float* bv    = (const float*)d_in[4];
  const float* Woff  = (const float*)d_in[5];
  const float* boff  = (const float*)d_in[6];
  const float* Wattn = (const float*)d_in[7];
  const float* battn = (const float*)d_in[8];
  const float* Wout  = (const float*)d_in[9];
  const float* bout  = (const float*)d_in[10];
  float* out = (float*)d_out;

  char* ws = (char*)d_ws;
  __hip_bfloat16* v = (__hip_bfloat16*)ws;        // 139,264,000 B
  size_t off = (size_t)BS * LEN_V * ED * 2;
  float* offs = (float*)(ws + off);               // 2400*384*4 = 3.69 MB
  off += (size_t)BS * LQ * 384 * 4;
  float* inner = (float*)(ws + off);              // 2400*256*4 = 2.46 MB
  off += (size_t)BS * LQ * 256 * 4;
  float* Wcat = (float*)(ws + off);               // 384*256*4
  off += (size_t)384 * ED * 4;
  float* bcat = (float*)(ws + off);               // 384*4

  const int M_Q = BS * LQ;  // 2400

  k_concat<<<384, 256, 0, stream>>>(Woff, boff, Wattn, battn, Wcat, bcat);
  // value proj: persistent full-N blocks, Wv resident in LDS, 16 waves/CU
  k_vproj<<<256, 1024, 0, stream>>>(value, Wv, bv, v);
  // query proj (offsets + attn logits): M=2400 -> 38 blocks, N=384 -> 6
  k_gemm64<float><<<dim3(38, 6), 256, 0, stream>>>(
      query, Wcat, bcat, offs, M_Q, 384);
  k_post<<<M_Q, 256, 0, stream>>>(refp, offs);
  k_sample<<<M_Q, 512, 0, stream>>>(v, offs, inner);
  // out proj: M=2400, N=256 -> (38, 4)
  k_gemm64<float><<<dim3(38, 4), 256, 0, stream>>>(
      inner, Wout, bout, out, M_Q, ED);
}